// Round 7
// baseline (209.736 us; speedup 1.0000x reference)
//
#include <hip/hip_runtime.h>

// y = W @ x + bias, W in COO (rows sorted), fp32.
// R12: R5 base with ONE schedule change — x-gathers issue BEFORE the
// barrier. R5's timeline exposed gather latency serially after the
// stream drain: streams -> zero -> barrier(drain) -> gathers -> wait ->
// accumulate. Here: cols load first, gathers issue immediately (compiler
// waits only on cols), pinned above the barrier by a memory-clobber asm;
// __syncthreads' vmcnt(0) drain then absorbs stream+gather latency in one
// overlapped wait. Decides between the two surviving theories for 78us:
//   (a) per-CU miss-queue cap (~64 lines): neutral -> ROOFLINE.
//   (b) per-wave in-flight duty cycle: 62-70us.
// Prior matrix: path L1-alloc(77.9)<glc(87.4)<LDS-DMA(87.9); CHUNK
// 4(118)/8(77.9)/16(91.9); monolithic(77.9)<pipelined(89.6); nt<plain.

constexpr int       CHUNK = 8;                        // nnz per thread
constexpr int       BLOCK = 256;
constexpr long long SPAN  = (long long)BLOCK * CHUNK; // 2048 nnz per block
constexpr int       RMAX  = 768;                      // LDS acc slots (3 KB)

typedef float vfloat4 __attribute__((ext_vector_type(4)));
typedef int   vint4   __attribute__((ext_vector_type(4)));

__global__ void init_y_bias(const float* __restrict__ bias,
                            float* __restrict__ y, int n) {
    int i = blockIdx.x * blockDim.x + threadIdx.x;
    if (i < n) y[i] = bias[i];
}

__device__ __forceinline__ void lds_add(float* p, float v) {
    // workgroup-scope relaxed fp add -> ds_add_f32 (no TCC involvement)
    __hip_atomic_fetch_add(p, v, __ATOMIC_RELAXED, __HIP_MEMORY_SCOPE_WORKGROUP);
}

__global__ __launch_bounds__(BLOCK) void spmv_coo_lds(
        const float* __restrict__ vals,
        const float* __restrict__ x,
        const int*   __restrict__ rows,
        const int*   __restrict__ cols,
        const float* __restrict__ bias,
        float*       __restrict__ y,
        long long nnz) {
    __shared__ float acc[RMAX];
    const int tid = threadIdx.x;
    const long long b0 = (long long)blockIdx.x * SPAN;
    if (b0 >= nnz) return;                       // whole block exits uniformly
    const long long bend = (b0 + SPAN < nnz) ? (b0 + SPAN) : nnz;
    const bool full = (b0 + SPAN) <= nnz;        // block-uniform

    float v[CHUNK]; int r[CHUNK]; int c[CHUNK]; float g[CHUNK];
    const long long i0 = b0 + (long long)tid * CHUNK;
    if (full) {
        // ---- cols FIRST: the gathers depend only on them ----
        const vint4* c4 = reinterpret_cast<const vint4*>(cols + i0);
        #pragma unroll
        for (int q = 0; q < CHUNK / 4; ++q) {
            vint4 cc = __builtin_nontemporal_load(c4 + q);
            #pragma unroll
            for (int j = 0; j < 4; ++j) c[4*q+j] = cc[j];
        }
        const vfloat4* v4 = reinterpret_cast<const vfloat4*>(vals + i0);
        const vint4*   r4 = reinterpret_cast<const vint4*>(rows + i0);
        #pragma unroll
        for (int q = 0; q < CHUNK / 4; ++q) {
            vfloat4 vv = __builtin_nontemporal_load(v4 + q);
            vint4   rr = __builtin_nontemporal_load(r4 + q);
            #pragma unroll
            for (int j = 0; j < 4; ++j) { v[4*q+j] = vv[j]; r[4*q+j] = rr[j]; }
        }
        // ---- issue all 8 gathers NOW (compiler waits only on cols);
        //      their latency hides under the zero-loop + barrier drain ----
        #pragma unroll
        for (int k = 0; k < CHUNK; ++k) g[k] = x[c[k]];
        // pin the gathers above the barrier: memory-clobber asm stops the
        // compiler sinking these (const-pointer) loads past the fence.
        // No data dependence on g here, so no waitcnt is forced.
        asm volatile("" ::: "memory");
    }

    // ---- prologue: fixed-size zero (overlaps stream+gather latency) ----
    #pragma unroll
    for (int i = tid; i < RMAX; i += BLOCK) acc[i] = 0.f;
    const int r0    = rows[b0];
    const int rl    = rows[bend - 1];
    const int range = rl - r0 + 1;
    __syncthreads();   // vmcnt(0)+lgkmcnt(0) drain: ONE overlapped wait

    if (range <= RMAX) {
        if (full) {
            int   cur = r[0];
            float sum = v[0] * g[0];
            #pragma unroll
            for (int k = 1; k < CHUNK; ++k) {
                if (r[k] != cur) {               // row boundary: flush run
                    lds_add(&acc[cur - r0], sum);
                    cur = r[k];
                    sum = 0.f;
                }
                sum += v[k] * g[k];
            }
            lds_add(&acc[cur - r0], sum);
        } else if (i0 < bend) {
            // scalar partial-block path (only the globally-last block)
            int   cur = rows[i0];
            float sum = 0.f;
            long long kend = (i0 + CHUNK < bend) ? (i0 + CHUNK) : bend;
            for (long long k = i0; k < kend; ++k) {
                int rk = rows[k];
                if (rk != cur) { lds_add(&acc[cur - r0], sum); sum = 0.f; cur = rk; }
                sum += vals[k] * x[cols[k]];
            }
            lds_add(&acc[cur - r0], sum);
        }
        __syncthreads();

        // ---- coalesced epilogue: interior rows exclusively owned ----
        for (int i = tid; i < range; i += BLOCK) {
            int   rr = r0 + i;
            float a  = acc[i];
            if (rr == r0 || rr == rl) {
                if (a != 0.f) atomicAdd(&y[rr], a);  // may span block boundary
            } else {
                y[rr] = bias[rr] + a;                // plain coalesced store
            }
        }
    } else {
        // pathological row-gap fallback: per-thread global atomics
        if (i0 < bend) {
            if (full) {
                int   cur = r[0];
                float sum = v[0] * g[0];
                #pragma unroll
                for (int k = 1; k < CHUNK; ++k) {
                    if (r[k] != cur) { atomicAdd(&y[cur], sum); sum = 0.f; cur = r[k]; }
                    sum += v[k] * g[k];
                }
                atomicAdd(&y[cur], sum);
            } else {
                int   cur = rows[i0];
                float sum = 0.f;
                long long kend = (i0 + CHUNK < bend) ? (i0 + CHUNK) : bend;
                for (long long k = i0; k < kend; ++k) {
                    int rk = rows[k];
                    if (rk != cur) { atomicAdd(&y[cur], sum); sum = 0.f; cur = rk; }
                    sum += vals[k] * x[cols[k]];
                }
                atomicAdd(&y[cur], sum);
            }
        }
    }
}

extern "C" void kernel_launch(void* const* d_in, const int* in_sizes, int n_in,
                              void* d_out, int out_size, void* d_ws, size_t ws_size,
                              hipStream_t stream) {
    const float* vals = (const float*)d_in[0];
    const float* x    = (const float*)d_in[1];
    const float* bias = (const float*)d_in[2];
    const int*   rows = (const int*)d_in[3];
    const int*   cols = (const int*)d_in[4];
    float* y = (float*)d_out;

    const long long nnz = in_sizes[0];
    const int n_rows    = in_sizes[2];   // len(bias) == n_rows

    // 1) y = bias (covers empty gap-rows + rows receiving boundary atomics)
    {
        int threads = 256;
        int blocks  = (n_rows + threads - 1) / threads;
        init_y_bias<<<blocks, threads, 0, stream>>>(bias, y, n_rows);
    }

    // 2) block-local LDS-accumulated COO reduce
    {
        long long blocks = (nnz + SPAN - 1) / SPAN;
        spmv_coo_lds<<<(int)blocks, BLOCK, 0, stream>>>(
            vals, x, rows, cols, bias, y, nnz);
    }
}